// Round 5
// baseline (1574.861 us; speedup 1.0000x reference)
//
#include <hip/hip_runtime.h>
#include <hip/hip_fp16.h>

#define NNODES   500000
#define BSHIFT   8
#define BSIZE    256
#define NBUCKET  1954          // ceil(N/256)
#define NBLK     977           // persistent blocks, 2 buckets each (co-resident: 4/CU * 256 CU = 1024)
#define NB_PAD   2048
#define GPLACE   512
#define ESEG_CAP 5856          // max edges per bucket staged in LDS (mean 4096, +27 sigma)
#define NCH      8
#define CHSHIFT  16            // chunk = src >> 16 (8 chunks cover 524288 >= N)
#define CNT2STR  9             // padded stride for per-thread chunk counters

// ---------------- software grid barrier (all NBLK blocks co-resident) ----------------
__device__ __forceinline__ void gbar(int* cnt, int target, bool fenced) {
    __syncthreads();
    if (threadIdx.x == 0) {
        if (fenced) __builtin_amdgcn_fence(__ATOMIC_RELEASE, "agent");  // flush L2 writes
        __hip_atomic_fetch_add(cnt, 1, __ATOMIC_RELAXED, __HIP_MEMORY_SCOPE_AGENT);
        while (__hip_atomic_load(cnt, __ATOMIC_RELAXED, __HIP_MEMORY_SCOPE_AGENT) < target)
            __builtin_amdgcn_s_sleep(2);
        if (fenced) __builtin_amdgcn_fence(__ATOMIC_ACQUIRE, "agent");  // invalidate L2/L1
    }
    __syncthreads();
}

// ---------------- pass 1: global histogram of dst buckets ----------------
__global__ __launch_bounds__(256) void hist_kernel(const int* __restrict__ dst,
                                                   int* __restrict__ bucket_count, int E) {
    __shared__ unsigned int h[NB_PAD];
    for (int i = threadIdx.x; i < NB_PAD; i += blockDim.x) h[i] = 0u;
    __syncthreads();
    int stride = gridDim.x * blockDim.x;
    for (int i = blockIdx.x * blockDim.x + threadIdx.x; i < E; i += stride)
        atomicAdd(&h[((unsigned)dst[i]) >> BSHIFT], 1u);
    __syncthreads();
    for (int b = threadIdx.x; b < NB_PAD; b += blockDim.x) {
        unsigned c = h[b];
        if (c) atomicAdd(&bucket_count[b], (int)c);
    }
}

// ---------------- pass 2: exclusive scan over 2048 buckets ----------------
__global__ __launch_bounds__(1024) void scan_kernel(const int* __restrict__ bc,
                                                    int* __restrict__ base,
                                                    int* __restrict__ cursor) {
    __shared__ int s[1024];
    int t = threadIdx.x;
    int a = bc[2 * t], b = bc[2 * t + 1];
    s[t] = a + b;
    __syncthreads();
    for (int off = 1; off < 1024; off <<= 1) {
        int v = (t >= off) ? s[t - off] : 0;
        __syncthreads();
        s[t] += v;
        __syncthreads();
    }
    int excl = s[t] - a - b;
    base[2 * t] = excl;     base[2 * t + 1] = excl + a;
    cursor[2 * t] = excl;   cursor[2 * t + 1] = excl + a;
    if (t == 1023) base[2048] = s[1023];
}

// ---------------- pass 3: place edges, packed = (dst&255)<<19 | src ----------------
__global__ __launch_bounds__(256) void place_kernel(const int* __restrict__ src,
                                                    const int* __restrict__ dst,
                                                    int* __restrict__ cursor,
                                                    unsigned int* __restrict__ packed,
                                                    int E, int C) {
    __shared__ unsigned int h[NB_PAD];
    __shared__ int cur[NB_PAD];
    for (int i = threadIdx.x; i < NB_PAD; i += blockDim.x) h[i] = 0u;
    __syncthreads();
    int lo = blockIdx.x * C;
    int hi = min(E, lo + C);
    for (int i = lo + threadIdx.x; i < hi; i += blockDim.x)
        atomicAdd(&h[((unsigned)dst[i]) >> BSHIFT], 1u);
    __syncthreads();
    for (int b = threadIdx.x; b < NB_PAD; b += blockDim.x) {
        unsigned c = h[b];
        cur[b] = c ? atomicAdd(&cursor[b], (int)c) : 0;
    }
    __syncthreads();
    for (int i = lo + threadIdx.x; i < hi; i += blockDim.x) {
        unsigned d = (unsigned)dst[i];
        unsigned b = d >> BSHIFT;
        int pos = atomicAdd(&cur[b], 1);
        packed[pos] = ((d & (unsigned)(BSIZE - 1)) << 19) | (unsigned)src[i];
    }
}

// ---------------- accumulate helpers ----------------
__device__ __forceinline__ void acc3(float* ap, uint2 w) {
    union { uint2 u2; __half2 h[2]; } g; g.u2 = w;
    float2 f01 = __half22float2(g.h[0]);
    float2 f23 = __half22float2(g.h[1]);
    atomicAdd(ap + 0, f01.x);
    atomicAdd(ap + 1, f01.y);
    atomicAdd(ap + 2, f23.x);
}
__device__ __forceinline__ void acc8(float* ap, uint4 w) {
    union { uint4 u4; __half2 h[4]; } g; g.u4 = w;
#pragma unroll
    for (int q = 0; q < 4; ++q) {
        float2 f = __half22float2(g.h[q]);
        atomicAdd(ap + 2 * q + 0, f.x);
        atomicAdd(ap + 2 * q + 1, f.y);
    }
}

// ---------------- fused persistent GCN kernel ----------------
__global__ __launch_bounds__(256, 4) void gcn_kernel(
    unsigned int* __restrict__ packed, const int* __restrict__ base,
    const float* __restrict__ x,
    const float* __restrict__ W1, const float* __restrict__ b1,
    const float* __restrict__ W2, const float* __restrict__ b2,
    __half* __restrict__ y1h, __half* __restrict__ y2h,
    float* __restrict__ out, int* __restrict__ gcnt)
{
    __shared__ float acc[2][BSIZE][17];                 // 34816 B, aliased as part-0 scratch
    __shared__ int sub[2][NCH + 1];                     // chunk boundaries per owned bucket
    unsigned int* lds_u = (unsigned int*)&acc[0][0][0];
    unsigned int* eseg  = lds_u;                        // [0, 5856)
    unsigned int* cnt2  = lds_u + ESEG_CAP;             // 256*9 = 2304
    unsigned int* cdeg  = lds_u + ESEG_CAP + 2304;      // 512
    int*          chtot = (int*)(lds_u + ESEG_CAP + 2304 + 512);  // 8   (total 8680 <= 8704)

    const int t = threadIdx.x;
    const int g = blockIdx.x;
    int barnum = 0;

    // ===== part 0: per-bucket degree count + in-place chunk sort =====
    for (int bk = 0; bk < 2; ++bk) {
        int b = 2 * g + bk;
        int beg = base[b], end = base[b + 1];
        int len = end - beg;
        for (int i = t; i < 256 * CNT2STR; i += 256) cnt2[i] = 0u;
        if (bk == 0) { cdeg[t] = 0u; cdeg[256 + t] = 0u; }
        __syncthreads();
        bool sortable = (len <= ESEG_CAP);
        if (sortable) {
            for (int k = t; k < len; k += 256) {
                unsigned p = packed[beg + k];
                eseg[k] = p;
                atomicAdd(&cdeg[(bk << 8) + (p >> 19)], 1u);
                cnt2[t * CNT2STR + ((p & 0x7FFFFu) >> CHSHIFT)]++;
            }
        } else {
            for (int k = t; k < len; k += 256) {
                unsigned p = packed[beg + k];
                atomicAdd(&cdeg[(bk << 8) + (p >> 19)], 1u);
            }
        }
        __syncthreads();
        if (t < NCH) {                                   // column-wise exclusive scan
            int run = 0;
            for (int tt = 0; tt < 256; ++tt) {
                int tmp = cnt2[tt * CNT2STR + t];
                cnt2[tt * CNT2STR + t] = run;
                run += tmp;
            }
            chtot[t] = run;
        }
        __syncthreads();
        if (t == 0) {
            if (sortable) {
                int run = beg;
                for (int c = 0; c < NCH; ++c) { sub[bk][c] = run; run += chtot[c]; }
                sub[bk][NCH] = end;
            } else {                                     // fallback: single mega-chunk
                sub[bk][0] = beg;
                for (int c = 1; c <= NCH; ++c) sub[bk][c] = end;
            }
        }
        __syncthreads();
        if (sortable) {
            for (int k = t; k < len; k += 256) {
                unsigned p = eseg[k];
                int c = (p & 0x7FFFFu) >> CHSHIFT;
                int pos = sub[bk][c] + (int)cnt2[t * CNT2STR + c];
                cnt2[t * CNT2STR + c]++;
                packed[pos] = p;
            }
        }
        __syncthreads();
    }

    // dinv + y1h + self-term registers
    int v0 = g * 512 + t;
    int v1 = v0 + 256;
    float di0 = rsqrtf((float)cdeg[t] + 1.0f);
    float di1 = rsqrtf((float)cdeg[256 + t] + 1.0f);
    float p00 = 0.f, p01 = 0.f, p02 = 0.f, p10 = 0.f, p11 = 0.f, p12 = 0.f;
    if (v0 < NNODES) {
        p00 = di0 * x[3 * v0 + 0]; p01 = di0 * x[3 * v0 + 1]; p02 = di0 * x[3 * v0 + 2];
        union { uint2 u; __half2 h[2]; } st;
        st.h[0] = __floats2half2_rn(p00, p01);
        st.h[1] = __floats2half2_rn(p02, 0.f);
        *(uint2*)(y1h + 4 * (size_t)v0) = st.u;
    }
    if (v1 < NNODES) {
        p10 = di1 * x[3 * v1 + 0]; p11 = di1 * x[3 * v1 + 1]; p12 = di1 * x[3 * v1 + 2];
        union { uint2 u; __half2 h[2]; } st;
        st.h[0] = __floats2half2_rn(p10, p11);
        st.h[1] = __floats2half2_rn(p12, 0.f);
        *(uint2*)(y1h + 4 * (size_t)v1) = st.u;
    }
    __syncthreads();
    for (int i = t; i < 2 * BSIZE * 17; i += 256) ((float*)acc)[i] = 0.f;
    ++barnum; gbar(gcnt, NBLK * barnum, true);          // y1h + sorted packed visible

    // ===== part A: layer-1 aggregation (chunk-ordered, 1 lane/edge, 8B gathers) =====
    for (int c = 0; c < NCH; ++c)
        for (int bk = 0; bk < 2; ++bk) {
            int s1e = sub[bk][c + 1];
            int i = sub[bk][c] + t;
            for (; i + 768 < s1e; i += 1024) {
                unsigned pw[4]; uint2 w[4];
#pragma unroll
                for (int u = 0; u < 4; ++u) pw[u] = packed[i + u * 256];
#pragma unroll
                for (int u = 0; u < 4; ++u)
                    w[u] = *(const uint2*)(y1h + 4 * (size_t)(pw[u] & 0x7FFFFu));
#pragma unroll
                for (int u = 0; u < 4; ++u) acc3(&acc[bk][pw[u] >> 19][0], w[u]);
            }
            for (; i < s1e; i += 256) {
                unsigned p = packed[i];
                uint2 w = *(const uint2*)(y1h + 4 * (size_t)(p & 0x7FFFFu));
                acc3(&acc[bk][p >> 19][0], w);
            }
        }
    __syncthreads();

    // epilogue 1: transform1 + relu, y2h = di * relu(W1^T a + b1)
    for (int bk = 0; bk < 2; ++bk) {
        int v = bk ? v1 : v0;
        if (v >= NNODES) continue;
        float di = bk ? di1 : di0;
        float a0 = di * acc[bk][t][0] + di * (bk ? p10 : p00);
        float a1 = di * acc[bk][t][1] + di * (bk ? p11 : p01);
        float a2 = di * acc[bk][t][2] + di * (bk ? p12 : p02);
        union { uint4 u[2]; __half2 h[8]; } st;
        float hf[16];
#pragma unroll
        for (int j = 0; j < 16; ++j) {
            float h = b1[j] + a0 * W1[j] + a1 * W1[16 + j] + a2 * W1[32 + j];
            hf[j] = di * fmaxf(h, 0.0f);
        }
#pragma unroll
        for (int q = 0; q < 8; ++q) st.h[q] = __floats2half2_rn(hf[2 * q], hf[2 * q + 1]);
        uint4* dp = (uint4*)(y2h + 16 * (size_t)v);
        dp[0] = st.u[0]; dp[1] = st.u[1];
    }
    __syncthreads();
    for (int i = t; i < 2 * BSIZE * 17; i += 256) ((float*)acc)[i] = 0.f;
    ++barnum; gbar(gcnt, NBLK * barnum, true);          // y2h visible

    // ===== part B: layer-2 aggregation, phased over 2 MB src windows =====
    int f2 = t & 1, slot = t >> 1;
    for (int c = 0; c < NCH; ++c) {
        for (int bk = 0; bk < 2; ++bk) {
            int s1e = sub[bk][c + 1];
            int i = sub[bk][c] + slot;
            for (; i + 384 < s1e; i += 512) {
                unsigned pw[4]; uint4 w[4];
#pragma unroll
                for (int u = 0; u < 4; ++u) pw[u] = packed[i + u * 128];
#pragma unroll
                for (int u = 0; u < 4; ++u)
                    w[u] = *(const uint4*)(y2h + 16 * (size_t)(pw[u] & 0x7FFFFu) + 8 * f2);
#pragma unroll
                for (int u = 0; u < 4; ++u) acc8(&acc[bk][pw[u] >> 19][8 * f2], w[u]);
            }
            for (; i < s1e; i += 128) {
                unsigned p = packed[i];
                uint4 w = *(const uint4*)(y2h + 16 * (size_t)(p & 0x7FFFFu) + 8 * f2);
                acc8(&acc[bk][p >> 19][8 * f2], w);
            }
        }
        if (c < NCH - 1) { ++barnum; gbar(gcnt, NBLK * barnum, false); }  // locality sync
    }
    __syncthreads();

    // epilogue 2: transform2 + log_softmax
    for (int bk = 0; bk < 2; ++bk) {
        int v = bk ? v1 : v0;
        if (v >= NNODES) continue;
        float di = bk ? di1 : di0;
        union { uint4 u[2]; __half2 h[8]; } sf;
        const uint4* sp = (const uint4*)(y2h + 16 * (size_t)v);
        sf.u[0] = sp[0]; sf.u[1] = sp[1];
        float a[16];
#pragma unroll
        for (int q = 0; q < 8; ++q) {
            float2 f = __half22float2(sf.h[q]);
            a[2 * q + 0] = di * (acc[bk][t][2 * q + 0] + f.x);
            a[2 * q + 1] = di * (acc[bk][t][2 * q + 1] + f.y);
        }
        float z[10];
#pragma unroll
        for (int j = 0; j < 10; ++j) {
            float s = b2[j];
#pragma unroll
            for (int k = 0; k < 16; ++k) s += a[k] * W2[k * 10 + j];
            z[j] = s;
        }
        float m = z[0];
#pragma unroll
        for (int j = 1; j < 10; ++j) m = fmaxf(m, z[j]);
        float sum = 0.0f;
#pragma unroll
        for (int j = 0; j < 10; ++j) sum += expf(z[j] - m);
        float lse = logf(sum);
        float* ov = out + 10 * (size_t)v;
#pragma unroll
        for (int j = 0; j < 10; ++j) ov[j] = z[j] - m - lse;
    }
}

extern "C" void kernel_launch(void* const* d_in, const int* in_sizes, int n_in,
                              void* d_out, int out_size, void* d_ws, size_t ws_size,
                              hipStream_t stream) {
    const float* x  = (const float*)d_in[0];
    const int*   ei = (const int*)d_in[1];
    const float* W1 = (const float*)d_in[2];
    const float* b1 = (const float*)d_in[3];
    const float* W2 = (const float*)d_in[4];
    const float* b2 = (const float*)d_in[5];
    float* out = (float*)d_out;

    const int E = in_sizes[1] / 2;            // 8,000,000
    const int* src = ei;
    const int* dst = ei + E;

    int*          ws_i         = (int*)d_ws;
    int*          bucket_count = ws_i;                    // [0, 2048)
    int*          gcnt         = ws_i + 2048;             // [2048]
    int*          base         = ws_i + 2052;             // [2052, 4101)
    int*          cursor       = ws_i + 4104;             // [4104, 6152)
    unsigned int* packed       = (unsigned int*)(ws_i + 6400);          // E words
    __half*       y1h          = (__half*)(packed + E);                 // 4N halves (2N words)
    __half*       y2h          = (__half*)(packed + E + 1000000);       // 16N halves (8N words)
    // total: 6400 + 8M + 1M + 4M words ~= 52 MB

    hipMemsetAsync(bucket_count, 0, 2052 * sizeof(int), stream);  // counts + gcnt

    const int B = 256;
    hist_kernel<<<GPLACE, B, 0, stream>>>(dst, bucket_count, E);
    scan_kernel<<<1, 1024, 0, stream>>>(bucket_count, base, cursor);
    int C = (E + GPLACE - 1) / GPLACE;
    place_kernel<<<GPLACE, B, 0, stream>>>(src, dst, cursor, packed, E, C);
    gcn_kernel<<<NBLK, B, 0, stream>>>(packed, base, x, W1, b1, W2, b2,
                                       y1h, y2h, out, gcnt);
}

// Round 6
// 1212.263 us; speedup vs baseline: 1.2991x; 1.2991x over previous
//
#include <hip/hip_runtime.h>
#include <hip/hip_fp16.h>

#define NNODES   500000
#define BSHIFT   8
#define BSIZE    256
#define NBUCKET  1954          // ceil(N/256)
#define NB_PAD   2048
#define GPLACE   512
#define ESEG_CAP 5888          // per-bucket LDS staging cap (mean 4096, +28 sigma)
#define NCH      8
#define CHSHIFT  16            // chunk = src >> 16

// ---------------- pass 1: global histogram of dst buckets ----------------
__global__ __launch_bounds__(256) void hist_kernel(const int* __restrict__ dst,
                                                   int* __restrict__ bucket_count, int E) {
    __shared__ unsigned int h[NB_PAD];
    for (int i = threadIdx.x; i < NB_PAD; i += blockDim.x) h[i] = 0u;
    __syncthreads();
    int stride = gridDim.x * blockDim.x;
    for (int i = blockIdx.x * blockDim.x + threadIdx.x; i < E; i += stride) {
        int d = __builtin_nontemporal_load(dst + i);
        atomicAdd(&h[((unsigned)d) >> BSHIFT], 1u);
    }
    __syncthreads();
    for (int b = threadIdx.x; b < NB_PAD; b += blockDim.x) {
        unsigned c = h[b];
        if (c) atomicAdd(&bucket_count[b], (int)c);
    }
}

// ---------------- pass 2: exclusive scan over 2048 buckets ----------------
__global__ __launch_bounds__(1024) void scan_kernel(const int* __restrict__ bc,
                                                    int* __restrict__ base,
                                                    int* __restrict__ cursor) {
    __shared__ int s[1024];
    int t = threadIdx.x;
    int a = bc[2 * t], b = bc[2 * t + 1];
    s[t] = a + b;
    __syncthreads();
    for (int off = 1; off < 1024; off <<= 1) {
        int v = (t >= off) ? s[t - off] : 0;
        __syncthreads();
        s[t] += v;
        __syncthreads();
    }
    int excl = s[t] - a - b;
    base[2 * t] = excl;     base[2 * t + 1] = excl + a;
    cursor[2 * t] = excl;   cursor[2 * t + 1] = excl + a;
    if (t == 1023) base[2048] = s[1023];
}

// ---------------- pass 3: place edges, packed = (dst&255)<<19 | src ----------------
__global__ __launch_bounds__(256) void place_kernel(const int* __restrict__ src,
                                                    const int* __restrict__ dst,
                                                    int* __restrict__ cursor,
                                                    unsigned int* __restrict__ packed,
                                                    int E, int C) {
    __shared__ unsigned int h[NB_PAD];
    __shared__ int cur[NB_PAD];
    for (int i = threadIdx.x; i < NB_PAD; i += blockDim.x) h[i] = 0u;
    __syncthreads();
    int lo = blockIdx.x * C;
    int hi = min(E, lo + C);
    for (int i = lo + threadIdx.x; i < hi; i += blockDim.x) {
        int d = __builtin_nontemporal_load(dst + i);
        atomicAdd(&h[((unsigned)d) >> BSHIFT], 1u);
    }
    __syncthreads();
    for (int b = threadIdx.x; b < NB_PAD; b += blockDim.x) {
        unsigned c = h[b];
        cur[b] = c ? atomicAdd(&cursor[b], (int)c) : 0;
    }
    __syncthreads();
    for (int i = lo + threadIdx.x; i < hi; i += blockDim.x) {
        unsigned d = (unsigned)dst[i];
        unsigned s = (unsigned)__builtin_nontemporal_load(src + i);
        unsigned b = d >> BSHIFT;
        int pos = atomicAdd(&cur[b], 1);
        packed[pos] = ((d & (unsigned)(BSIZE - 1)) << 19) | s;
    }
}

// ---------------- pass 4: per-bucket chunk-sort (by src>>16) + degree -> dinv ----------------
__global__ __launch_bounds__(256) void sortdinv_kernel(unsigned int* __restrict__ packed,
                                                       const int* __restrict__ base,
                                                       float* __restrict__ dinv, int n) {
    __shared__ unsigned int   eseg[ESEG_CAP];            // 23.5 KB
    __shared__ unsigned short cnt2[256 * 9];             // 4.6 KB, per-thread chunk counts
    __shared__ unsigned int   cdeg[BSIZE];               // 1 KB
    __shared__ int            chtot[NCH];
    __shared__ int            starts[NCH];

    const int t = threadIdx.x;
    const int b = blockIdx.x;
    int beg = base[b], end = base[b + 1];
    int len = end - beg;

    for (int c = 0; c < 9; ++c) cnt2[t * 9 + c] = 0;
    cdeg[t] = 0u;
    __syncthreads();

    bool sortable = (len <= ESEG_CAP);
    if (sortable) {
        for (int k = t; k < len; k += 256) {
            unsigned p = __builtin_nontemporal_load(packed + beg + k);
            eseg[k] = p;
            atomicAdd(&cdeg[p >> 19], 1u);
            cnt2[t * 9 + ((p & 0x7FFFFu) >> CHSHIFT)]++;
        }
    } else {
        for (int k = t; k < len; k += 256) {
            unsigned p = packed[beg + k];
            atomicAdd(&cdeg[p >> 19], 1u);
        }
    }
    __syncthreads();

    if (t < NCH) {                                       // column-wise exclusive scan
        int run = 0;
        for (int tt = 0; tt < 256; ++tt) {
            int tmp = cnt2[tt * 9 + t];
            cnt2[tt * 9 + t] = (unsigned short)run;
            run += tmp;
        }
        chtot[t] = run;
    }
    __syncthreads();
    if (t == 0) {
        int run = 0;
        for (int c = 0; c < NCH; ++c) { starts[c] = run; run += chtot[c]; }
    }
    __syncthreads();

    if (sortable) {                                      // replay in identical per-thread order
        for (int k = t; k < len; k += 256) {
            unsigned p = eseg[k];
            int c = (p & 0x7FFFFu) >> CHSHIFT;
            int off = cnt2[t * 9 + c];
            cnt2[t * 9 + c] = (unsigned short)(off + 1);
            packed[beg + starts[c] + off] = p;
        }
    }

    int v = (b << BSHIFT) + t;
    if (v < n) dinv[v] = rsqrtf((float)cdeg[t] + 1.0f);
}

// ---------------- y1h = fp16(dinv * x), stride 4 halves ----------------
__global__ __launch_bounds__(256) void y1_kernel(const float* __restrict__ dinv,
                                                 const float* __restrict__ x,
                                                 __half* __restrict__ y1h, int n) {
    int v = blockIdx.x * blockDim.x + threadIdx.x;
    if (v >= n) return;
    float di = dinv[v];
    union { uint2 u; __half2 h[2]; } st;
    st.h[0] = __floats2half2_rn(di * x[3 * v + 0], di * x[3 * v + 1]);
    st.h[1] = __floats2half2_rn(di * x[3 * v + 2], 0.0f);
    *(uint2*)(y1h + 4 * (size_t)v) = st.u;
}

// ---------------- layer 1: 1 lane/edge, 8B gather, LDS acc (pad 5), fused transform ----------------
__global__ __launch_bounds__(256) void agg1t1_kernel(const unsigned int* __restrict__ packed,
                                                     const int* __restrict__ base,
                                                     const __half* __restrict__ y1h,
                                                     const float* __restrict__ dinv,
                                                     const float* __restrict__ x,
                                                     const float* __restrict__ W1,
                                                     const float* __restrict__ b1,
                                                     __half* __restrict__ y2h, int n) {
    __shared__ float acc[BSIZE * 5];
    int b = blockIdx.x;
    for (int i = threadIdx.x; i < BSIZE * 5; i += blockDim.x) acc[i] = 0.0f;
    __syncthreads();
    int beg = base[b], end = base[b + 1];
    const int STR = 256;
    int i = beg + threadIdx.x;
    for (; i + 7 * STR < end; i += 8 * STR) {
        unsigned p[8]; uint2 w[8];
#pragma unroll
        for (int u = 0; u < 8; ++u) p[u] = __builtin_nontemporal_load(packed + i + u * STR);
#pragma unroll
        for (int u = 0; u < 8; ++u)
            w[u] = *(const uint2*)(y1h + 4 * (size_t)(p[u] & 0x7FFFFu));
#pragma unroll
        for (int u = 0; u < 8; ++u) {
            unsigned dl = p[u] >> 19;
            float* ap = acc + dl * 5;
            union { uint2 u2; __half2 h[2]; } g; g.u2 = w[u];
            float2 f01 = __half22float2(g.h[0]);
            float2 f23 = __half22float2(g.h[1]);
            atomicAdd(ap + 0, f01.x);
            atomicAdd(ap + 1, f01.y);
            atomicAdd(ap + 2, f23.x);
        }
    }
    for (; i < end; i += STR) {
        unsigned p = packed[i];
        union { uint2 u2; __half2 h[2]; } g;
        g.u2 = *(const uint2*)(y1h + 4 * (size_t)(p & 0x7FFFFu));
        float2 f01 = __half22float2(g.h[0]);
        float2 f23 = __half22float2(g.h[1]);
        float* ap = acc + (p >> 19) * 5;
        atomicAdd(ap + 0, f01.x);
        atomicAdd(ap + 1, f01.y);
        atomicAdd(ap + 2, f23.x);
    }
    __syncthreads();
    int t = threadIdx.x;
    int v = (b << BSHIFT) + t;
    if (v >= n) return;
    float di = dinv[v];
    float a0 = di * (acc[t * 5 + 0] + di * x[3 * v + 0]);
    float a1 = di * (acc[t * 5 + 1] + di * x[3 * v + 1]);
    float a2 = di * (acc[t * 5 + 2] + di * x[3 * v + 2]);
    float hf[16];
#pragma unroll
    for (int j = 0; j < 16; ++j) {
        float h = b1[j] + a0 * W1[j] + a1 * W1[16 + j] + a2 * W1[32 + j];
        hf[j] = di * fmaxf(h, 0.0f);
    }
    union { uint4 u[2]; __half2 h[8]; } st;
#pragma unroll
    for (int q = 0; q < 8; ++q) st.h[q] = __floats2half2_rn(hf[2 * q], hf[2 * q + 1]);
    uint4* dp = (uint4*)(y2h + 16 * (size_t)v);
    dp[0] = st.u[0];
    dp[1] = st.u[1];
}

// ---------------- layer 2: 2 lanes/edge, 16B gathers, LDS acc (pad 17), fused transform ----------------
__global__ __launch_bounds__(256) void agg2t2_kernel(const unsigned int* __restrict__ packed,
                                                     const int* __restrict__ base,
                                                     const __half* __restrict__ y2h,
                                                     const float* __restrict__ dinv,
                                                     const float* __restrict__ W2,
                                                     const float* __restrict__ b2,
                                                     float* __restrict__ out, int n) {
    __shared__ float acc[BSIZE * 17];
    int b = blockIdx.x;
    for (int i = threadIdx.x; i < BSIZE * 17; i += blockDim.x) acc[i] = 0.0f;
    __syncthreads();
    int beg = base[b], end = base[b + 1];
    int f2 = threadIdx.x & 1;
    int slot = threadIdx.x >> 1;
    const int STR = 128;
    int i = beg + slot;
    for (; i + 7 * STR < end; i += 8 * STR) {
        unsigned p[8]; uint4 w[8];
#pragma unroll
        for (int u = 0; u < 8; ++u) p[u] = __builtin_nontemporal_load(packed + i + u * STR);
#pragma unroll
        for (int u = 0; u < 8; ++u)
            w[u] = *(const uint4*)(y2h + 16 * (size_t)(p[u] & 0x7FFFFu) + 8 * f2);
#pragma unroll
        for (int u = 0; u < 8; ++u) {
            float* ap = acc + (p[u] >> 19) * 17 + 8 * f2;
            union { uint4 u4; __half2 h[4]; } g; g.u4 = w[u];
#pragma unroll
            for (int q = 0; q < 4; ++q) {
                float2 f = __half22float2(g.h[q]);
                atomicAdd(ap + 2 * q + 0, f.x);
                atomicAdd(ap + 2 * q + 1, f.y);
            }
        }
    }
    for (; i < end; i += STR) {
        unsigned p = packed[i];
        union { uint4 u4; __half2 h[4]; } g;
        g.u4 = *(const uint4*)(y2h + 16 * (size_t)(p & 0x7FFFFu) + 8 * f2);
        float* ap = acc + (p >> 19) * 17 + 8 * f2;
#pragma unroll
        for (int q = 0; q < 4; ++q) {
            float2 f = __half22float2(g.h[q]);
            atomicAdd(ap + 2 * q + 0, f.x);
            atomicAdd(ap + 2 * q + 1, f.y);
        }
    }
    __syncthreads();
    int t = threadIdx.x;
    int v = (b << BSHIFT) + t;
    if (v >= n) return;
    float di = dinv[v];
    union { uint4 u[2]; __half2 h[8]; } sf;
    const uint4* sp = (const uint4*)(y2h + 16 * (size_t)v);
    sf.u[0] = sp[0];
    sf.u[1] = sp[1];
    float a[16];
#pragma unroll
    for (int q = 0; q < 8; ++q) {
        float2 f = __half22float2(sf.h[q]);
        a[2 * q + 0] = di * (acc[t * 17 + 2 * q + 0] + f.x);
        a[2 * q + 1] = di * (acc[t * 17 + 2 * q + 1] + f.y);
    }
    float z[10];
#pragma unroll
    for (int j = 0; j < 10; ++j) {
        float s = b2[j];
#pragma unroll
        for (int k = 0; k < 16; ++k) s += a[k] * W2[k * 10 + j];
        z[j] = s;
    }
    float m = z[0];
#pragma unroll
    for (int j = 1; j < 10; ++j) m = fmaxf(m, z[j]);
    float sum = 0.0f;
#pragma unroll
    for (int j = 0; j < 10; ++j) sum += expf(z[j] - m);
    float lse = logf(sum);
    float* ov = out + 10 * (size_t)v;
#pragma unroll
    for (int j = 0; j < 10; ++j) ov[j] = z[j] - m - lse;
}

extern "C" void kernel_launch(void* const* d_in, const int* in_sizes, int n_in,
                              void* d_out, int out_size, void* d_ws, size_t ws_size,
                              hipStream_t stream) {
    const float* x  = (const float*)d_in[0];
    const int*   ei = (const int*)d_in[1];
    const float* W1 = (const float*)d_in[2];
    const float* b1 = (const float*)d_in[3];
    const float* W2 = (const float*)d_in[4];
    const float* b2 = (const float*)d_in[5];
    float* out = (float*)d_out;

    const int E = in_sizes[1] / 2;            // 8,000,000
    const int* src = ei;
    const int* dst = ei + E;

    int*          ws_i         = (int*)d_ws;
    int*          bucket_count = ws_i;                           // 2048
    int*          base         = ws_i + 2048;                    // 2049
    int*          cursor       = ws_i + 4104;                    // 2048
    unsigned int* packed       = (unsigned int*)(ws_i + 6400);   // E
    float*        dinv         = (float*)(packed + E);           // N
    __half*       y1h          = (__half*)(dinv + NNODES);       // 4N halves
    __half*       y2h          = y1h + (size_t)4 * NNODES;       // 16N halves

    hipMemsetAsync(bucket_count, 0, NB_PAD * sizeof(int), stream);

    const int B = 256;
    hist_kernel<<<GPLACE, B, 0, stream>>>(dst, bucket_count, E);
    scan_kernel<<<1, 1024, 0, stream>>>(bucket_count, base, cursor);
    int C = (E + GPLACE - 1) / GPLACE;
    place_kernel<<<GPLACE, B, 0, stream>>>(src, dst, cursor, packed, E, C);
    sortdinv_kernel<<<NBUCKET, B, 0, stream>>>(packed, base, dinv, NNODES);
    y1_kernel<<<(NNODES + B - 1) / B, B, 0, stream>>>(dinv, x, y1h, NNODES);
    agg1t1_kernel<<<NBUCKET, B, 0, stream>>>(packed, base, y1h, dinv, x, W1, b1, y2h, NNODES);
    agg2t2_kernel<<<NBUCKET, B, 0, stream>>>(packed, base, y2h, dinv, W2, b2, out, NNODES);
}

// Round 7
// 638.459 us; speedup vs baseline: 2.4667x; 1.8987x over previous
//
#include <hip/hip_runtime.h>
#include <hip/hip_fp16.h>

#define NNODES   500000
#define BSHIFT   8
#define BSIZE    256
#define NBUCKET  1954          // ceil(N/256)
#define NB_PAD   2048
#define GPLACE   512
#define ESEG_CAP 8192          // per-bucket LDS staging cap (Poisson mean 3906, +68 sigma)

// ---------------- pass 1: global histogram of dst buckets ----------------
__global__ __launch_bounds__(256) void hist_kernel(const int* __restrict__ dst,
                                                   int* __restrict__ bucket_count, int E) {
    __shared__ unsigned int h[NB_PAD];
    for (int i = threadIdx.x; i < NB_PAD; i += blockDim.x) h[i] = 0u;
    __syncthreads();
    int stride = gridDim.x * blockDim.x;
    for (int i = blockIdx.x * blockDim.x + threadIdx.x; i < E; i += stride) {
        int d = __builtin_nontemporal_load(dst + i);
        atomicAdd(&h[((unsigned)d) >> BSHIFT], 1u);
    }
    __syncthreads();
    for (int b = threadIdx.x; b < NB_PAD; b += blockDim.x) {
        unsigned c = h[b];
        if (c) atomicAdd(&bucket_count[b], (int)c);
    }
}

// ---------------- pass 2: exclusive scan over 2048 buckets ----------------
__global__ __launch_bounds__(1024) void scan_kernel(const int* __restrict__ bc,
                                                    int* __restrict__ base,
                                                    int* __restrict__ cursor) {
    __shared__ int s[1024];
    int t = threadIdx.x;
    int a = bc[2 * t], b = bc[2 * t + 1];
    s[t] = a + b;
    __syncthreads();
    for (int off = 1; off < 1024; off <<= 1) {
        int v = (t >= off) ? s[t - off] : 0;
        __syncthreads();
        s[t] += v;
        __syncthreads();
    }
    int excl = s[t] - a - b;
    base[2 * t] = excl;     base[2 * t + 1] = excl + a;
    cursor[2 * t] = excl;   cursor[2 * t + 1] = excl + a;
    if (t == 1023) base[2048] = s[1023];
}

// ---------------- pass 3: place edges, packed = (dst&255)<<19 | src ----------------
__global__ __launch_bounds__(256) void place_kernel(const int* __restrict__ src,
                                                    const int* __restrict__ dst,
                                                    int* __restrict__ cursor,
                                                    unsigned int* __restrict__ packed,
                                                    int E, int C) {
    __shared__ unsigned int h[NB_PAD];
    __shared__ int cur[NB_PAD];
    for (int i = threadIdx.x; i < NB_PAD; i += blockDim.x) h[i] = 0u;
    __syncthreads();
    int lo = blockIdx.x * C;
    int hi = min(E, lo + C);
    for (int i = lo + threadIdx.x; i < hi; i += blockDim.x) {
        int d = __builtin_nontemporal_load(dst + i);
        atomicAdd(&h[((unsigned)d) >> BSHIFT], 1u);
    }
    __syncthreads();
    for (int b = threadIdx.x; b < NB_PAD; b += blockDim.x) {
        unsigned c = h[b];
        cur[b] = c ? atomicAdd(&cursor[b], (int)c) : 0;
    }
    __syncthreads();
    for (int i = lo + threadIdx.x; i < hi; i += blockDim.x) {
        unsigned d = (unsigned)dst[i];
        unsigned s = (unsigned)__builtin_nontemporal_load(src + i);
        unsigned b = d >> BSHIFT;
        int pos = atomicAdd(&cur[b], 1);
        packed[pos] = ((d & (unsigned)(BSIZE - 1)) << 19) | s;
    }
}

// ---------------- pass 4: in-bucket counting sort by dst-low-8 -> exact CSR ----------------
// Also emits row_ptr (CSR), dinv, and y1h = fp16(dinv*x). Edge words become bare src.
__global__ __launch_bounds__(256) void sortcsr_kernel(unsigned int* __restrict__ packed,
                                                      const int* __restrict__ base,
                                                      int* __restrict__ row_ptr,
                                                      float* __restrict__ dinv,
                                                      const float* __restrict__ x,
                                                      __half* __restrict__ y1h,
                                                      unsigned int* __restrict__ scratch,
                                                      int* __restrict__ lock, int n) {
    __shared__ unsigned int eseg[ESEG_CAP];   // 32 KB
    __shared__ unsigned int cdeg[BSIZE];
    __shared__ int sc[BSIZE];
    __shared__ int cur[BSIZE];

    const int t = threadIdx.x;
    const int b = blockIdx.x;
    int beg = base[b], end = base[b + 1];
    int len = end - beg;

    cdeg[t] = 0u;
    __syncthreads();

    bool sortable = (len <= ESEG_CAP);
    if (sortable) {
        for (int k = t; k < len; k += 256) {
            unsigned p = __builtin_nontemporal_load(packed + beg + k);
            eseg[k] = p;
            atomicAdd(&cdeg[p >> 19], 1u);
        }
    } else {
        for (int k = t; k < len; k += 256)
            atomicAdd(&cdeg[packed[beg + k] >> 19], 1u);
    }
    __syncthreads();

    // exclusive scan of cdeg over 256 threads
    int myc = (int)cdeg[t];
    sc[t] = myc;
    __syncthreads();
    for (int off = 1; off < 256; off <<= 1) {
        int v = (t >= off) ? sc[t - off] : 0;
        __syncthreads();
        sc[t] += v;
        __syncthreads();
    }
    int excl = sc[t] - myc;
    cur[t] = excl;

    // CSR row_ptr + dinv + y1h
    int v = (b << BSHIFT) + t;
    if (v < n) {
        row_ptr[v] = beg + excl;
        if (v == n - 1) row_ptr[n] = beg + excl + myc;
        float di = rsqrtf((float)myc + 1.0f);
        dinv[v] = di;
        union { uint2 u; __half2 h[2]; } st;
        st.h[0] = __floats2half2_rn(di * x[3 * v + 0], di * x[3 * v + 1]);
        st.h[1] = __floats2half2_rn(di * x[3 * v + 2], 0.0f);
        *(uint2*)(y1h + 4 * (size_t)v) = st.u;
    }
    __syncthreads();

    if (sortable) {
        for (int k = t; k < len; k += 256) {
            unsigned p = eseg[k];
            int pos = atomicAdd(&cur[p >> 19], 1);
            packed[beg + pos] = p & 0x7FFFFu;      // keep src only
        }
    } else {
        // unreachable for valid inputs (>68 sigma); serialized global-scratch path
        if (t == 0)
            while (__hip_atomic_exchange(lock, 1, __ATOMIC_ACQUIRE, __HIP_MEMORY_SCOPE_AGENT))
                __builtin_amdgcn_s_sleep(8);
        __syncthreads();
        for (int k = t; k < len; k += 256) {
            unsigned p = packed[beg + k];
            int pos = atomicAdd(&cur[p >> 19], 1);
            scratch[pos] = p & 0x7FFFFu;
        }
        __syncthreads();
        for (int k = t; k < len; k += 256) packed[beg + k] = scratch[k];
        __syncthreads();
        if (t == 0) __hip_atomic_store(lock, 0, __ATOMIC_RELEASE, __HIP_MEMORY_SCOPE_AGENT);
    }
}

// ---------------- layer 1: node-centric register accumulation + fused transform ----------------
__global__ __launch_bounds__(256) void agg1t1_kernel(const unsigned int* __restrict__ eidx,
                                                     const int* __restrict__ row_ptr,
                                                     const __half* __restrict__ y1h,
                                                     const float* __restrict__ dinv,
                                                     const float* __restrict__ W1,
                                                     const float* __restrict__ b1,
                                                     __half* __restrict__ y2h, int n) {
    int v = blockIdx.x * 256 + threadIdx.x;
    if (v >= n) return;
    int beg = row_ptr[v], end = row_ptr[v + 1];
    // self term: y1h[v] = di*x[v]
    union { uint2 u2; __half2 h[2]; } sf;
    sf.u2 = *(const uint2*)(y1h + 4 * (size_t)v);
    float2 f01 = __half22float2(sf.h[0]);
    float2 f23 = __half22float2(sf.h[1]);
    float a0 = f01.x, a1 = f01.y, a2 = f23.x;
    int i = beg;
    for (; i + 3 < end; i += 4) {
        unsigned e0 = eidx[i], e1 = eidx[i + 1], e2 = eidx[i + 2], e3 = eidx[i + 3];
        uint2 w0 = *(const uint2*)(y1h + 4 * (size_t)e0);
        uint2 w1 = *(const uint2*)(y1h + 4 * (size_t)e1);
        uint2 w2 = *(const uint2*)(y1h + 4 * (size_t)e2);
        uint2 w3 = *(const uint2*)(y1h + 4 * (size_t)e3);
        uint2 ww[4] = {w0, w1, w2, w3};
#pragma unroll
        for (int u = 0; u < 4; ++u) {
            union { uint2 u2; __half2 h[2]; } g; g.u2 = ww[u];
            float2 p01 = __half22float2(g.h[0]);
            float2 p23 = __half22float2(g.h[1]);
            a0 += p01.x; a1 += p01.y; a2 += p23.x;
        }
    }
    for (; i < end; ++i) {
        unsigned e = eidx[i];
        union { uint2 u2; __half2 h[2]; } g;
        g.u2 = *(const uint2*)(y1h + 4 * (size_t)e);
        float2 p01 = __half22float2(g.h[0]);
        float2 p23 = __half22float2(g.h[1]);
        a0 += p01.x; a1 += p01.y; a2 += p23.x;
    }
    float di = dinv[v];
    a0 *= di; a1 *= di; a2 *= di;
    float hf[16];
#pragma unroll
    for (int j = 0; j < 16; ++j) {
        float h = b1[j] + a0 * W1[j] + a1 * W1[16 + j] + a2 * W1[32 + j];
        hf[j] = di * fmaxf(h, 0.0f);
    }
    union { uint4 u[2]; __half2 h[8]; } st;
#pragma unroll
    for (int q = 0; q < 8; ++q) st.h[q] = __floats2half2_rn(hf[2 * q], hf[2 * q + 1]);
    uint4* dp = (uint4*)(y2h + 16 * (size_t)v);
    dp[0] = st.u[0];
    dp[1] = st.u[1];
}

// ---------------- layer 2: node-centric register accumulation + fused transform ----------------
__device__ __forceinline__ void addh8(float* a, uint4 w) {
    union { uint4 u4; __half2 h[4]; } g; g.u4 = w;
#pragma unroll
    for (int q = 0; q < 4; ++q) {
        float2 f = __half22float2(g.h[q]);
        a[2 * q + 0] += f.x;
        a[2 * q + 1] += f.y;
    }
}

__global__ __launch_bounds__(256) void agg2t2_kernel(const unsigned int* __restrict__ eidx,
                                                     const int* __restrict__ row_ptr,
                                                     const __half* __restrict__ y2h,
                                                     const float* __restrict__ dinv,
                                                     const float* __restrict__ W2,
                                                     const float* __restrict__ b2,
                                                     float* __restrict__ out, int n) {
    int v = blockIdx.x * 256 + threadIdx.x;
    if (v >= n) return;
    int beg = row_ptr[v], end = row_ptr[v + 1];
    float a[16];
    {   // self term: y2h[v]
        const uint4* sp = (const uint4*)(y2h + 16 * (size_t)v);
        uint4 s0 = sp[0], s1 = sp[1];
        union { uint4 u4; __half2 h[4]; } g;
        g.u4 = s0;
#pragma unroll
        for (int q = 0; q < 4; ++q) {
            float2 f = __half22float2(g.h[q]);
            a[2 * q] = f.x; a[2 * q + 1] = f.y;
        }
        g.u4 = s1;
#pragma unroll
        for (int q = 0; q < 4; ++q) {
            float2 f = __half22float2(g.h[q]);
            a[8 + 2 * q] = f.x; a[8 + 2 * q + 1] = f.y;
        }
    }
    int i = beg;
    for (; i + 1 < end; i += 2) {
        unsigned e0 = eidx[i], e1 = eidx[i + 1];
        const uint4* p0 = (const uint4*)(y2h + 16 * (size_t)e0);
        const uint4* p1 = (const uint4*)(y2h + 16 * (size_t)e1);
        uint4 w0a = p0[0], w0b = p0[1], w1a = p1[0], w1b = p1[1];
        addh8(a, w0a); addh8(a + 8, w0b);
        addh8(a, w1a); addh8(a + 8, w1b);
    }
    if (i < end) {
        unsigned e = eidx[i];
        const uint4* p = (const uint4*)(y2h + 16 * (size_t)e);
        uint4 wa = p[0], wb = p[1];
        addh8(a, wa); addh8(a + 8, wb);
    }
    float di = dinv[v];
#pragma unroll
    for (int k = 0; k < 16; ++k) a[k] *= di;
    float z[10];
#pragma unroll
    for (int j = 0; j < 10; ++j) {
        float s = b2[j];
#pragma unroll
        for (int k = 0; k < 16; ++k) s += a[k] * W2[k * 10 + j];
        z[j] = s;
    }
    float m = z[0];
#pragma unroll
    for (int j = 1; j < 10; ++j) m = fmaxf(m, z[j]);
    float sum = 0.0f;
#pragma unroll
    for (int j = 0; j < 10; ++j) sum += expf(z[j] - m);
    float lse = logf(sum);
    float* ov = out + 10 * (size_t)v;
#pragma unroll
    for (int j = 0; j < 10; ++j) ov[j] = z[j] - m - lse;
}

extern "C" void kernel_launch(void* const* d_in, const int* in_sizes, int n_in,
                              void* d_out, int out_size, void* d_ws, size_t ws_size,
                              hipStream_t stream) {
    const float* x  = (const float*)d_in[0];
    const int*   ei = (const int*)d_in[1];
    const float* W1 = (const float*)d_in[2];
    const float* b1 = (const float*)d_in[3];
    const float* W2 = (const float*)d_in[4];
    const float* b2 = (const float*)d_in[5];
    float* out = (float*)d_out;

    const int E = in_sizes[1] / 2;            // 8,000,000
    const int* src = ei;
    const int* dst = ei + E;

    int*          ws_i         = (int*)d_ws;
    int*          bucket_count = ws_i;                            // 2048
    int*          base         = ws_i + 2048;                     // 2049
    int*          cursor       = ws_i + 4104;                     // 2048
    int*          lock         = ws_i + 6152;                     // 1
    int*          row_ptr      = ws_i + 6400;                     // N+1
    float*        dinv         = (float*)(ws_i + 506408);         // N
    unsigned int* packed       = (unsigned int*)(ws_i + 1006408); // E
    __half*       y1h          = (__half*)(ws_i + 1006408 + E);   // 4N halves (1M words)
    __half*       y2h          = (__half*)(ws_i + 2006408 + E);   // 16N halves (4M words)
    // total ~ 14.0M words = 56 MB

    hipMemsetAsync(ws_i, 0, 6400 * sizeof(int), stream);          // counts + lock

    const int B = 256;
    hist_kernel<<<GPLACE, B, 0, stream>>>(dst, bucket_count, E);
    scan_kernel<<<1, 1024, 0, stream>>>(bucket_count, base, cursor);
    int C = (E + GPLACE - 1) / GPLACE;
    place_kernel<<<GPLACE, B, 0, stream>>>(src, dst, cursor, packed, E, C);
    sortcsr_kernel<<<NBUCKET, B, 0, stream>>>(packed, base, row_ptr, dinv, x, y1h,
                                              (unsigned int*)y2h, lock, NNODES);
    agg1t1_kernel<<<NBUCKET, B, 0, stream>>>(packed, row_ptr, y1h, dinv, W1, b1, y2h, NNODES);
    agg2t2_kernel<<<NBUCKET, B, 0, stream>>>(packed, row_ptr, y2h, dinv, W2, b2, out, NNODES);
}